// Round 1
// baseline (571.378 us; speedup 1.0000x reference)
//
#include <hip/hip_runtime.h>

// Problem constants
#define NBATCH 8
#define CIN    64
#define HIN    256
#define WIN    256
#define COUT   128
#define HOUT   254
#define WOUT   254

// Tiling: block computes 128 pixels (4 rows x 32 cols) x 128 couts.
// K-loop: 9 taps x 2 chunks of 32 ci, 16x16x32 bf16 MFMA.
#define PROWS  4
#define PCOLS  32
#define XR     (PROWS + 2)   // 6 input rows
#define XC     (PCOLS + 2)   // 34 input cols
#define CIP    72            // padded ci stride in bf16 units (72*2B=144B=36 words
                             // -> b128 frag reads hit all 32 banks evenly)

typedef __attribute__((ext_vector_type(8))) short bf16x8;  // MFMA A/B frag (4 VGPRs)
typedef __attribute__((ext_vector_type(4))) float f32x4;   // MFMA C/D frag

__device__ __forceinline__ unsigned short f2bf(float f) {
    union { float f; unsigned u; } v; v.f = f;
    unsigned r = v.u + 0x7FFF + ((v.u >> 16) & 1);   // round-to-nearest-even
    return (unsigned short)(r >> 16);
}

// mish(v) = v*tanh(softplus(v)); t=e^v: tanh(log1p(t)) = (t^2+2t)/(t^2+2t+2).
__device__ __forceinline__ float mish1(float v) {
    float t = __expf(v);
    float u = t * t + 2.0f * t;
    float r = v * __fdividef(u, u + 2.0f);
    return (v > 20.0f) ? v : r;
}
__device__ __forceinline__ float mish2(float v) { return mish1(mish1(v)); }

// Pre-transpose weights: wgt[co][ci][kh][kw] fp32 -> wT[tap][co][ci] bf16.
__global__ __launch_bounds__(256) void wtrans_kernel(
    const float* __restrict__ wgt, unsigned short* __restrict__ wT)
{
    int i = blockIdx.x * 256 + threadIdx.x;       // over 9*128*64 = 73728
    if (i >= 9 * COUT * CIN) return;
    int ci  = i & (CIN - 1);
    int co  = (i >> 6) & (COUT - 1);
    int tap = i >> 13;
    wT[i] = f2bf(wgt[(co * CIN + ci) * 9 + tap]);
}

// ---------------------------------------------------------------------------
// Fast path: B fragments are loaded straight from wT (147 KB total, L1/L2-
// resident, identical for every block) into registers each tap. No sw LDS
// buffer, no barriers inside the tap loop — exactly ONE __syncthreads in the
// kernel (protecting the x-tile stage). LDS = 29.4 KB -> up to 5 blocks/CU.
// ---------------------------------------------------------------------------
__global__ __launch_bounds__(256) void conv_mfma_ws(
    const float* __restrict__ x,                  // [NB][CIN][HIN][WIN]
    const float* __restrict__ bias,               // [COUT]
    const unsigned short* __restrict__ wT,        // [9][COUT][CIN] bf16
    float* __restrict__ out)                      // [NB][COUT][HOUT][WOUT]
{
    __shared__ unsigned short sx[XR * XC * CIP];  // 6*34*72*2 = 29376 B

    const int tid = threadIdx.x;
    const int wt  = blockIdx.x;                   // 0..7  (w tile)
    const int ht  = blockIdx.y;                   // 0..63 (h tile)
    const int n   = blockIdx.z;                   // 0..7
    const int oh0 = ht * PROWS, ow0 = wt * PCOLS;

    const float* xn = x + (size_t)n * CIN * HIN * WIN;

    // ---- stage x tile once: [r][c][ci] bf16, ci contiguous (padded to CIP).
    for (int j = tid; j < XR * XC * (CIN / 2); j += 256) {
        int c = j % XC;
        int t = j / XC;
        int r = t % XR;
        int p = t / XR;                           // ci pair index 0..31
        int gh = oh0 + r; if (gh > HIN - 1) gh = HIN - 1;   // clamped rows/cols only
        int gw = ow0 + c; if (gw > WIN - 1) gw = WIN - 1;   // feed never-stored outputs
        const float* src = xn + (p * 2) * (HIN * WIN) + gh * WIN + gw;
        float f0 = src[0];
        float f1 = src[HIN * WIN];
        unsigned pk = (unsigned)f2bf(f0) | ((unsigned)f2bf(f1) << 16);
        ((unsigned*)sx)[(r * XC + c) * (CIP / 2) + p] = pk;
    }

    // wave/lane decomposition: 4 waves, each computes 64 px x 64 co
    const int w    = tid >> 6;
    const int lane = tid & 63;
    const int m    = lane & 15;                   // A: pixel row / B: cout col
    const int g    = lane >> 4;                   // k-group (8 ci each)
    const int px0  = (w & 1) * 64;
    const int cb   = (w >> 1) * 64;

    int slot0[4];                                 // (r*XC + c) per M-subtile
    #pragma unroll
    for (int mt = 0; mt < 4; ++mt) {
        int px = px0 + mt * 16 + m;
        slot0[mt] = (px >> 5) * XC + (px & 31);
    }
    int bco[4];                                   // wT element offset per N-subtile
    #pragma unroll
    for (int nt = 0; nt < 4; ++nt)
        bco[nt] = (cb + nt * 16 + m) * CIN + g * 8;

    f32x4 acc[4][4];
    #pragma unroll
    for (int a = 0; a < 4; ++a)
        #pragma unroll
        for (int b = 0; b < 4; ++b)
            acc[a][b] = (f32x4){0.f, 0.f, 0.f, 0.f};

    __syncthreads();                              // the only barrier

    #pragma unroll 1                              // keep register pressure bounded
    for (int tap = 0; tap < 9; ++tap) {
        int kh = tap / 3, kw = tap - kh * 3;
        const unsigned short* wq = wT + tap * (COUT * CIN);

        // B fragments for this tap: 8 x b128 global loads, all L1/L2 hits
        // (16 KB/tap slice shared by all 4096 blocks). Issued up front so
        // they overlap the A ds_reads and the first MFMAs.
        bf16x8 bv[2][4];
        #pragma unroll
        for (int ck = 0; ck < 2; ++ck)
            #pragma unroll
            for (int nt = 0; nt < 4; ++nt)
                bv[ck][nt] = *(const bf16x8*)(wq + bco[nt] + ck * 32);

        const int aoff = (kh * XC + kw) * CIP + g * 8;
        #pragma unroll
        for (int ck = 0; ck < 2; ++ck) {
            bf16x8 av[4];
            #pragma unroll
            for (int mt = 0; mt < 4; ++mt)
                av[mt] = *(const bf16x8*)&sx[slot0[mt] * CIP + aoff + ck * 32];
            #pragma unroll
            for (int mt = 0; mt < 4; ++mt)
                #pragma unroll
                for (int nt = 0; nt < 4; ++nt)
                    acc[mt][nt] = __builtin_amdgcn_mfma_f32_16x16x32_bf16(
                        av[mt], bv[ck][nt], acc[mt][nt], 0, 0, 0);
        }
    }

    // ---- epilogue: bias + mish2 + store.
    // C/D layout (m89-verified): col(n-dim)=lane&15, row(m-dim)=(lane>>4)*4+reg.
    #pragma unroll
    for (int nt = 0; nt < 4; ++nt) {
        int co = cb + nt * 16 + m;
        float bs = bias[co];
        float* ob = out + (size_t)(n * COUT + co) * HOUT * WOUT;
        #pragma unroll
        for (int mt = 0; mt < 4; ++mt) {
            int pb = px0 + mt * 16 + g * 4;
            int oh = oh0 + (pb >> 5);
            int ow = ow0 + (pb & 31);
            if (oh >= HOUT) continue;
            float v0 = mish2(acc[mt][nt][0] + bs);
            float v1 = mish2(acc[mt][nt][1] + bs);
            float v2 = mish2(acc[mt][nt][2] + bs);
            float v3 = mish2(acc[mt][nt][3] + bs);
            float* dst = ob + oh * WOUT + ow;
            if (ow + 3 < WOUT) {
                dst[0] = v0; dst[1] = v1; dst[2] = v2; dst[3] = v3;
            } else {
                if (ow     < WOUT) dst[0] = v0;
                if (ow + 1 < WOUT) dst[1] = v1;
                if (ow + 2 < WOUT) dst[2] = v2;
                if (ow + 3 < WOUT) dst[3] = v3;
            }
        }
    }
}

// ---------------------------------------------------------------------------
// Fallback (no workspace): original per-tap LDS weight staging from fp32 wgt.
// Only used if ws_size is too small for wT.
// ---------------------------------------------------------------------------
__global__ __launch_bounds__(256) void conv_mfma_fb(
    const float* __restrict__ x,
    const float* __restrict__ wgt,                // [COUT][CIN][3][3]
    const float* __restrict__ bias,
    float* __restrict__ out)
{
    __shared__ unsigned short sx[XR * XC * CIP];
    __shared__ unsigned short sw[COUT * CIP];

    const int tid = threadIdx.x;
    const int wt  = blockIdx.x;
    const int ht  = blockIdx.y;
    const int n   = blockIdx.z;
    const int oh0 = ht * PROWS, ow0 = wt * PCOLS;

    const float* xn = x + (size_t)n * CIN * HIN * WIN;

    for (int j = tid; j < XR * XC * (CIN / 2); j += 256) {
        int c = j % XC;
        int t = j / XC;
        int r = t % XR;
        int p = t / XR;
        int gh = oh0 + r; if (gh > HIN - 1) gh = HIN - 1;
        int gw = ow0 + c; if (gw > WIN - 1) gw = WIN - 1;
        const float* src = xn + (p * 2) * (HIN * WIN) + gh * WIN + gw;
        float f0 = src[0];
        float f1 = src[HIN * WIN];
        unsigned pk = (unsigned)f2bf(f0) | ((unsigned)f2bf(f1) << 16);
        ((unsigned*)sx)[(r * XC + c) * (CIP / 2) + p] = pk;
    }

    const int w    = tid >> 6;
    const int lane = tid & 63;
    const int m    = lane & 15;
    const int g    = lane >> 4;
    const int px0  = (w & 1) * 64;
    const int cb   = (w >> 1) * 64;

    int slot0[4];
    #pragma unroll
    for (int mt = 0; mt < 4; ++mt) {
        int px = px0 + mt * 16 + m;
        slot0[mt] = (px >> 5) * XC + (px & 31);
    }
    int bbase[4];
    #pragma unroll
    for (int nt = 0; nt < 4; ++nt)
        bbase[nt] = (cb + nt * 16 + m) * CIP + g * 8;

    f32x4 acc[4][4];
    #pragma unroll
    for (int a = 0; a < 4; ++a)
        #pragma unroll
        for (int b = 0; b < 4; ++b)
            acc[a][b] = (f32x4){0.f, 0.f, 0.f, 0.f};

    for (int tap = 0; tap < 9; ++tap) {
        int kh = tap / 3, kw = tap - kh * 3;
        __syncthreads();
        for (int i = tid; i < COUT * CIN; i += 256) {
            int co = i >> 6, ci = i & 63;
            sw[co * CIP + ci] = f2bf(wgt[(co * CIN + ci) * 9 + tap]);
        }
        __syncthreads();

        const int aoff = (kh * XC + kw) * CIP + g * 8;
        #pragma unroll
        for (int ck = 0; ck < 2; ++ck) {
            bf16x8 av[4], bv[4];
            #pragma unroll
            for (int mt = 0; mt < 4; ++mt)
                av[mt] = *(const bf16x8*)&sx[slot0[mt] * CIP + aoff + ck * 32];
            #pragma unroll
            for (int nt = 0; nt < 4; ++nt)
                bv[nt] = *(const bf16x8*)&sw[bbase[nt] + ck * 32];
            #pragma unroll
            for (int mt = 0; mt < 4; ++mt)
                #pragma unroll
                for (int nt = 0; nt < 4; ++nt)
                    acc[mt][nt] = __builtin_amdgcn_mfma_f32_16x16x32_bf16(
                        av[mt], bv[nt], acc[mt][nt], 0, 0, 0);
        }
    }

    #pragma unroll
    for (int nt = 0; nt < 4; ++nt) {
        int co = cb + nt * 16 + m;
        float bs = bias[co];
        float* ob = out + (size_t)(n * COUT + co) * HOUT * WOUT;
        #pragma unroll
        for (int mt = 0; mt < 4; ++mt) {
            int pb = px0 + mt * 16 + g * 4;
            int oh = oh0 + (pb >> 5);
            int ow = ow0 + (pb & 31);
            if (oh >= HOUT) continue;
            float v0 = mish2(acc[mt][nt][0] + bs);
            float v1 = mish2(acc[mt][nt][1] + bs);
            float v2 = mish2(acc[mt][nt][2] + bs);
            float v3 = mish2(acc[mt][nt][3] + bs);
            float* dst = ob + oh * WOUT + ow;
            if (ow + 3 < WOUT) {
                dst[0] = v0; dst[1] = v1; dst[2] = v2; dst[3] = v3;
            } else {
                if (ow     < WOUT) dst[0] = v0;
                if (ow + 1 < WOUT) dst[1] = v1;
                if (ow + 2 < WOUT) dst[2] = v2;
                if (ow + 3 < WOUT) dst[3] = v3;
            }
        }
    }
}

extern "C" void kernel_launch(void* const* d_in, const int* in_sizes, int n_in,
                              void* d_out, int out_size, void* d_ws, size_t ws_size,
                              hipStream_t stream) {
    const float* x    = (const float*)d_in[0];
    const float* wgt  = (const float*)d_in[1];
    const float* bias = (const float*)d_in[2];
    float* out        = (float*)d_out;

    const size_t need = (size_t)9 * COUT * CIN * sizeof(unsigned short);  // 147456 B
    int use_ws = (ws_size >= need) ? 1 : 0;
    unsigned short* wT = (unsigned short*)d_ws;

    dim3 grid((WOUT + PCOLS - 1) / PCOLS,   // 8
              (HOUT + PROWS - 1) / PROWS,   // 64
              NBATCH);                      // 8

    if (use_ws) {
        wtrans_kernel<<<(9 * COUT * CIN + 255) / 256, 256, 0, stream>>>(wgt, wT);
        conv_mfma_ws<<<grid, 256, 0, stream>>>(x, bias, wT, out);
    } else {
        conv_mfma_fb<<<grid, 256, 0, stream>>>(x, wgt, bias, out);
    }
}

// Round 4
// 497.006 us; speedup vs baseline: 1.1496x; 1.1496x over previous
//
#include <hip/hip_runtime.h>

// Problem constants
#define NBATCH 8
#define CIN    64
#define HIN    256
#define WIN    256
#define COUT   128
#define HOUT   254
#define WOUT   254

// Tiling: block computes 128 pixels (4 rows x 32 cols) x 128 couts.
// K-loop: 9 taps x 2 chunks of 32 ci, 16x16x32 bf16 MFMA.
#define PROWS  4
#define PCOLS  32
#define XR     (PROWS + 2)   // 6 input rows
#define XC     (PCOLS + 2)   // 34 input cols
#define CIP    72            // padded ci stride in bf16 units (72*2B=144B=36 words
                             // -> b128 frag reads spread evenly over banks)

typedef __attribute__((ext_vector_type(8))) short bf16x8;  // MFMA A/B frag (4 VGPRs)
typedef __attribute__((ext_vector_type(4))) float f32x4;   // MFMA C/D frag

__device__ __forceinline__ unsigned short f2bf(float f) {
    union { float f; unsigned u; } v; v.f = f;
    unsigned r = v.u + 0x7FFF + ((v.u >> 16) & 1);   // round-to-nearest-even
    return (unsigned short)(r >> 16);
}

// mish(v) = v*tanh(softplus(v)); t=e^v: tanh(log1p(t)) = (t^2+2t)/(t^2+2t+2).
__device__ __forceinline__ float mish1(float v) {
    float t = __expf(v);
    float u = t * t + 2.0f * t;
    float r = v * __fdividef(u, u + 2.0f);
    return (v > 20.0f) ? v : r;
}
__device__ __forceinline__ float mish2(float v) { return mish1(mish1(v)); }

// Pre-transpose weights: wgt[co][ci][kh][kw] fp32 -> wT[tap][co][ci] bf16.
__global__ __launch_bounds__(256) void wtrans_kernel(
    const float* __restrict__ wgt, unsigned short* __restrict__ wT)
{
    int i = blockIdx.x * 256 + threadIdx.x;       // over 9*128*64 = 73728
    if (i >= 9 * COUT * CIN) return;
    int ci  = i & (CIN - 1);
    int co  = (i >> 6) & (COUT - 1);
    int tap = i >> 13;
    wT[i] = f2bf(wgt[(co * CIN + ci) * 9 + tap]);
}

// ---------------------------------------------------------------------------
// r0 structure (LDS-staged weights, 2 barriers/tap) + T14 async-STAGE split:
// tap t+1's wT global loads are issued BEFORE the post-write barrier, and that
// barrier is a single asm "s_waitcnt lgkmcnt(0); s_barrier" (no vmcnt drain),
// so the loads stay in flight across the whole tap-t MFMA phase.
// ---------------------------------------------------------------------------
__global__ __launch_bounds__(256, 3) void conv_mfma_ws(
    const float* __restrict__ x,                  // [NB][CIN][HIN][WIN]
    const float* __restrict__ bias,               // [COUT]
    const unsigned short* __restrict__ wT,        // [9][COUT][CIN] bf16
    float* __restrict__ out)                      // [NB][COUT][HOUT][WOUT]
{
    __shared__ unsigned short sx[XR * XC * CIP];  // 29376 B
    __shared__ unsigned short sw[COUT * CIP];     // 18432 B

    const int tid = threadIdx.x;
    const int wt  = blockIdx.x;                   // 0..7  (w tile)
    const int ht  = blockIdx.y;                   // 0..63 (h tile)
    const int n   = blockIdx.z;                   // 0..7
    const int oh0 = ht * PROWS, ow0 = wt * PCOLS;

    const float* xn = x + (size_t)n * CIN * HIN * WIN;

    // ---- prologue: issue tap-0 weight loads first (deepest latency hiding)
    bf16x8 wr0 = *(const bf16x8*)(wT + (tid      ) * 8);
    bf16x8 wr1 = *(const bf16x8*)(wT + (tid + 256) * 8);
    bf16x8 wr2 = *(const bf16x8*)(wT + (tid + 512) * 8);
    bf16x8 wr3 = *(const bf16x8*)(wT + (tid + 768) * 8);

    // ---- stage x tile: [r][c][ci] bf16, ci contiguous (padded to CIP).
    // Main part (c<32): pure-shift addressing, gw provably in bounds.
    #pragma unroll 4
    for (int k = 0; k < 24; ++k) {
        int u = tid + k * 256;                    // 0..6143
        int r = u >> 10;                          // 0..5
        int v = u & 1023;
        int c = v & 31;                           // 0..31
        int p = v >> 5;                           // ci pair 0..31
        int gh = oh0 + r; if (gh > HIN - 1) gh = HIN - 1;
        int gw = ow0 + c;                         // <= 224+31 = 255, in bounds
        const float* src = xn + (size_t)(p * 2) * (HIN * WIN) + gh * WIN + gw;
        float f0 = src[0];
        float f1 = src[HIN * WIN];
        unsigned pk = (unsigned)f2bf(f0) | ((unsigned)f2bf(f1) << 16);
        ((unsigned*)sx)[(r * XC + c) * (CIP / 2) + p] = pk;
    }
    // Edge cols c=32,33: 6 r x 2 c x 32 p = 384 units, 256 threads -> 2 passes.
    // (r3 bugfix: "if (tid < 384)" left r=4,5 unstaged with 256 threads.)
    #pragma unroll
    for (int e = tid; e < 384; e += 256) {
        int r = e >> 6;                           // 0..5
        int rem = e & 63;
        int c = 32 + (rem >> 5);                  // 32..33
        int p = rem & 31;
        int gh = oh0 + r; if (gh > HIN - 1) gh = HIN - 1;
        int gw = ow0 + c; if (gw > WIN - 1) gw = WIN - 1;
        const float* src = xn + (size_t)(p * 2) * (HIN * WIN) + gh * WIN + gw;
        float f0 = src[0];
        float f1 = src[HIN * WIN];
        unsigned pk = (unsigned)f2bf(f0) | ((unsigned)f2bf(f1) << 16);
        ((unsigned*)sx)[(r * XC + c) * (CIP / 2) + p] = pk;
    }

    // wave/lane decomposition: 4 waves, each computes 64 px x 64 co
    const int w    = tid >> 6;
    const int lane = tid & 63;
    const int m    = lane & 15;                   // A: pixel row / B: cout col
    const int g    = lane >> 4;                   // k-group (8 ci each)
    const int px0  = (w & 1) * 64;
    const int cb   = (w >> 1) * 64;

    int slot0[4];                                 // (r*XC + c) per M-subtile
    #pragma unroll
    for (int mt = 0; mt < 4; ++mt) {
        int px = px0 + mt * 16 + m;
        slot0[mt] = (px >> 5) * XC + (px & 31);
    }
    int bbase[4];
    #pragma unroll
    for (int nt = 0; nt < 4; ++nt)
        bbase[nt] = (cb + nt * 16 + m) * CIP + g * 8;

    f32x4 acc[4][4];
    #pragma unroll
    for (int a = 0; a < 4; ++a)
        #pragma unroll
        for (int b = 0; b < 4; ++b)
            acc[a][b] = (f32x4){0.f, 0.f, 0.f, 0.f};

    // sw write slots (static per thread)
    const int sw0 = ((tid      ) >> 3) * CIP + ((tid      ) & 7) * 8;
    const int sw1 = ((tid + 256) >> 3) * CIP + ((tid + 256) & 7) * 8;
    const int sw2 = ((tid + 512) >> 3) * CIP + ((tid + 512) & 7) * 8;
    const int sw3 = ((tid + 768) >> 3) * CIP + ((tid + 768) & 7) * 8;

    #pragma unroll 1
    for (int tap = 0; tap < 9; ++tap) {
        // (a) full barrier: all waves done reading sw[tap-1]; 1st iter also
        // covers the sx stage. In-flight wT loads were issued a whole tap
        // ago -> the vmcnt(0) drain here is nearly free.
        __syncthreads();

        *(bf16x8*)&sw[sw0] = wr0;
        *(bf16x8*)&sw[sw1] = wr1;
        *(bf16x8*)&sw[sw2] = wr2;
        *(bf16x8*)&sw[sw3] = wr3;

        if (tap < 8) {                            // issue NEXT tap's loads now
            const unsigned short* wp = wT + (tap + 1) * (COUT * CIN);
            wr0 = *(const bf16x8*)(wp + (tid      ) * 8);
            wr1 = *(const bf16x8*)(wp + (tid + 256) * 8);
            wr2 = *(const bf16x8*)(wp + (tid + 512) * 8);
            wr3 = *(const bf16x8*)(wp + (tid + 768) * 8);
        }

        // (b) raw barrier: wait ONLY the ds_writes (lgkmcnt), leave the
        // just-issued global loads (vmcnt) in flight across the MFMA phase.
        // Single asm block so nothing can be interposed between wait+barrier.
        asm volatile("s_waitcnt lgkmcnt(0)\n\ts_barrier" ::: "memory");

        const int kh = tap / 3, kw = tap - kh * 3;
        const int aoff = (kh * XC + kw) * CIP + g * 8;

        __builtin_amdgcn_s_setprio(1);
        #pragma unroll
        for (int ck = 0; ck < 2; ++ck) {
            bf16x8 av[4], bv[4];
            #pragma unroll
            for (int mt = 0; mt < 4; ++mt)
                av[mt] = *(const bf16x8*)&sx[slot0[mt] * CIP + aoff + ck * 32];
            #pragma unroll
            for (int nt = 0; nt < 4; ++nt)
                bv[nt] = *(const bf16x8*)&sw[bbase[nt] + ck * 32];
            #pragma unroll
            for (int mt = 0; mt < 4; ++mt)
                #pragma unroll
                for (int nt = 0; nt < 4; ++nt)
                    acc[mt][nt] = __builtin_amdgcn_mfma_f32_16x16x32_bf16(
                        av[mt], bv[nt], acc[mt][nt], 0, 0, 0);
        }
        __builtin_amdgcn_s_setprio(0);
    }

    // ---- epilogue: bias + mish2 + store.
    // C/D layout (m89-verified): col(n-dim)=lane&15, row(m-dim)=(lane>>4)*4+reg.
    #pragma unroll
    for (int nt = 0; nt < 4; ++nt) {
        int co = cb + nt * 16 + m;
        float bs = bias[co];
        float* ob = out + (size_t)(n * COUT + co) * HOUT * WOUT;
        #pragma unroll
        for (int mt = 0; mt < 4; ++mt) {
            int pb = px0 + mt * 16 + g * 4;
            int oh = oh0 + (pb >> 5);
            int ow = ow0 + (pb & 31);
            if (oh >= HOUT) continue;
            float v0 = mish2(acc[mt][nt][0] + bs);
            float v1 = mish2(acc[mt][nt][1] + bs);
            float v2 = mish2(acc[mt][nt][2] + bs);
            float v3 = mish2(acc[mt][nt][3] + bs);
            float* dst = ob + oh * WOUT + ow;
            if (ow + 3 < WOUT) {
                dst[0] = v0; dst[1] = v1; dst[2] = v2; dst[3] = v3;
            } else {
                if (ow     < WOUT) dst[0] = v0;
                if (ow + 1 < WOUT) dst[1] = v1;
                if (ow + 2 < WOUT) dst[2] = v2;
                if (ow + 3 < WOUT) dst[3] = v3;
            }
        }
    }
}

// ---------------------------------------------------------------------------
// Fallback (no workspace): per-tap LDS weight staging from fp32 wgt.
// ---------------------------------------------------------------------------
__global__ __launch_bounds__(256) void conv_mfma_fb(
    const float* __restrict__ x,
    const float* __restrict__ wgt,                // [COUT][CIN][3][3]
    const float* __restrict__ bias,
    float* __restrict__ out)
{
    __shared__ unsigned short sx[XR * XC * CIP];
    __shared__ unsigned short sw[COUT * CIP];

    const int tid = threadIdx.x;
    const int wt  = blockIdx.x;
    const int ht  = blockIdx.y;
    const int n   = blockIdx.z;
    const int oh0 = ht * PROWS, ow0 = wt * PCOLS;

    const float* xn = x + (size_t)n * CIN * HIN * WIN;

    for (int j = tid; j < XR * XC * (CIN / 2); j += 256) {
        int c = j % XC;
        int t = j / XC;
        int r = t % XR;
        int p = t / XR;
        int gh = oh0 + r; if (gh > HIN - 1) gh = HIN - 1;
        int gw = ow0 + c; if (gw > WIN - 1) gw = WIN - 1;
        const float* src = xn + (p * 2) * (HIN * WIN) + gh * WIN + gw;
        float f0 = src[0];
        float f1 = src[HIN * WIN];
        unsigned pk = (unsigned)f2bf(f0) | ((unsigned)f2bf(f1) << 16);
        ((unsigned*)sx)[(r * XC + c) * (CIP / 2) + p] = pk;
    }

    const int w    = tid >> 6;
    const int lane = tid & 63;
    const int m    = lane & 15;
    const int g    = lane >> 4;
    const int px0  = (w & 1) * 64;
    const int cb   = (w >> 1) * 64;

    int slot0[4];
    #pragma unroll
    for (int mt = 0; mt < 4; ++mt) {
        int px = px0 + mt * 16 + m;
        slot0[mt] = (px >> 5) * XC + (px & 31);
    }
    int bbase[4];
    #pragma unroll
    for (int nt = 0; nt < 4; ++nt)
        bbase[nt] = (cb + nt * 16 + m) * CIP + g * 8;

    f32x4 acc[4][4];
    #pragma unroll
    for (int a = 0; a < 4; ++a)
        #pragma unroll
        for (int b = 0; b < 4; ++b)
            acc[a][b] = (f32x4){0.f, 0.f, 0.f, 0.f};

    for (int tap = 0; tap < 9; ++tap) {
        int kh = tap / 3, kw = tap - kh * 3;
        __syncthreads();
        for (int i = tid; i < COUT * CIN; i += 256) {
            int co = i >> 6, ci = i & 63;
            sw[co * CIP + ci] = f2bf(wgt[(co * CIN + ci) * 9 + tap]);
        }
        __syncthreads();

        const int aoff = (kh * XC + kw) * CIP + g * 8;
        #pragma unroll
        for (int ck = 0; ck < 2; ++ck) {
            bf16x8 av[4], bv[4];
            #pragma unroll
            for (int mt = 0; mt < 4; ++mt)
                av[mt] = *(const bf16x8*)&sx[slot0[mt] * CIP + aoff + ck * 32];
            #pragma unroll
            for (int nt = 0; nt < 4; ++nt)
                bv[nt] = *(const bf16x8*)&sw[bbase[nt] + ck * 32];
            #pragma unroll
            for (int mt = 0; mt < 4; ++mt)
                #pragma unroll
                for (int nt = 0; nt < 4; ++nt)
                    acc[mt][nt] = __builtin_amdgcn_mfma_f32_16x16x32_bf16(
                        av[mt], bv[nt], acc[mt][nt], 0, 0, 0);
        }
    }

    #pragma unroll
    for (int nt = 0; nt < 4; ++nt) {
        int co = cb + nt * 16 + m;
        float bs = bias[co];
        float* ob = out + (size_t)(n * COUT + co) * HOUT * WOUT;
        #pragma unroll
        for (int mt = 0; mt < 4; ++mt) {
            int pb = px0 + mt * 16 + g * 4;
            int oh = oh0 + (pb >> 5);
            int ow = ow0 + (pb & 31);
            if (oh >= HOUT) continue;
            float v0 = mish2(acc[mt][nt][0] + bs);
            float v1 = mish2(acc[mt][nt][1] + bs);
            float v2 = mish2(acc[mt][nt][2] + bs);
            float v3 = mish2(acc[mt][nt][3] + bs);
            float* dst = ob + oh * WOUT + ow;
            if (ow + 3 < WOUT) {
                dst[0] = v0; dst[1] = v1; dst[2] = v2; dst[3] = v3;
            } else {
                if (ow     < WOUT) dst[0] = v0;
                if (ow + 1 < WOUT) dst[1] = v1;
                if (ow + 2 < WOUT) dst[2] = v2;
                if (ow + 3 < WOUT) dst[3] = v3;
            }
        }
    }
}

extern "C" void kernel_launch(void* const* d_in, const int* in_sizes, int n_in,
                              void* d_out, int out_size, void* d_ws, size_t ws_size,
                              hipStream_t stream) {
    const float* x    = (const float*)d_in[0];
    const float* wgt  = (const float*)d_in[1];
    const float* bias = (const float*)d_in[2];
    float* out        = (float*)d_out;

    const size_t need = (size_t)9 * COUT * CIN * sizeof(unsigned short);  // 147456 B
    int use_ws = (ws_size >= need) ? 1 : 0;
    unsigned short* wT = (unsigned short*)d_ws;

    dim3 grid((WOUT + PCOLS - 1) / PCOLS,   // 8
              (HOUT + PROWS - 1) / PROWS,   // 64
              NBATCH);                      // 8

    if (use_ws) {
        wtrans_kernel<<<(9 * COUT * CIN + 255) / 256, 256, 0, stream>>>(wgt, wT);
        conv_mfma_ws<<<grid, 256, 0, stream>>>(x, bias, wT, out);
    } else {
        conv_mfma_fb<<<grid, 256, 0, stream>>>(x, wgt, bias, out);
    }
}